// Round 7
// baseline (148.035 us; speedup 1.0000x reference)
//
#include <hip/hip_runtime.h>
#include <math.h>

// ChamferLoss: pred [32,4096,3] f32, gt [32,4096,3] f32 -> scalar f32.
//
// R11. R10 (70us main) counters: MfmaUtil 19.4 (13.6us busy vs 4us useful
// floor - K=32 shape for 24 slots), VALUBusy 37 (26us), ~40% idle (LDS
// 51.7KB -> 3 blocks/CU vs grid wanting 4 -> dispatch tail; 1M LDS atomic
// conflicts = 4 lanes/address). R11:
//  - mfma_f32_32x32x16_bf16 with 2-WAY bf16 split: x=h+m -> (h+m)(h+m)
//    exact = 12 slots + g2(h,m)*1 + 1*p2(h,m) = K=16 exactly. Halves MFMA
//    cycles, halves Bfrag (4MB), halves staging bytes per pair. Numerics:
//    coord error ~2^-18 rel -> d2 ~3e-5 abs -> output ~1e-4 << 6.25e-3.
//  - Block = 64 gt rows x 4096 cols, 8 waves = rw(2) x cq(4), 1 A-frag per
//    wave: VGPR ~55 -> __launch_bounds__(512,8); LDS 16+16+1 = 33.3KB ->
//    4 blocks/CU = 32 waves/CU; grid 2048 = exactly 2 clean passes.
//  - LDS atomicMin now 64 lanes -> 32 contiguous addresses (2-way, cheap).
//  - prep absorbs wspred init (drops the 512KB memset launch).
//
// Layouts (m74/m101-verified, 32x32x16 bf16):
//   A: row = lane&31, k = 8*(lane>>5)+i
//   B: col = lane&31, k = 8*(lane>>5)+i
//   C: col = lane&31, row = (reg&3) + 8*(reg>>2) + 4*(lane>>5)
// K-slot map (A = -2*gt split h/m, B = pred split h/m):
//   k0-2  : Ah*Bh (x,y,z)      k3-5  : Ah*Bm (x,y,z)
//   k6-8  : Am*Bh (x,y,z)      k9-11 : Am*Bm (x,y,z)
//   k12-13: G2h,G2m * 1        k14-15: 1 * P2h,P2m
//   => acc = d2 = p2 + g2 - 2*dot directly.

typedef short short8 __attribute__((ext_vector_type(8)));
typedef float f32x16 __attribute__((ext_vector_type(16)));
typedef unsigned int uint;

#define NPTS  4096
#define TPBM  512           // 8 waves = rw(2) x cq(4)
#define TPBP  256
#define NPANEL 64           // gt row-panels of 64 per batch
#define GRID_MAIN (32 * NPANEL)              // 2048
#define NBT   128           // B-tiles per batch (32 cols each)
#define CHT   4             // tiles per cq per chunk
#define NCH   8             // 32 tiles/cq / CHT
#define ONEB ((short)0x3F80)                 // bf16 1.0

// ---- bf16 split helpers (RNE) ----
__device__ __forceinline__ unsigned short bf16h(float f) {
    uint u = __float_as_uint(f);
    uint r = u + 0x7FFFu + ((u >> 16) & 1u);
    return (unsigned short)(r >> 16);
}
__device__ __forceinline__ float bf16f(unsigned short h) {
    return __uint_as_float(((uint)h) << 16);
}
struct Split2 { unsigned short h, m; };
__device__ __forceinline__ Split2 split2(float x) {
    Split2 s;
    s.h = bf16h(x);
    s.m = bf16h(x - bf16f(s.h));
    return s;
}

// ---- prep: pred -> B-fragments + wspred init (one thread per frag-lane) ----
__global__ __launch_bounds__(TPBP) void chamfer_prep(
    const float* __restrict__ pred, short8* __restrict__ Bfrag,
    uint* __restrict__ wspred)
{
    const int gid = blockIdx.x * TPBP + threadIdx.x;   // 262144 total
    if (gid < 32 * NPTS) wspred[gid] = 0xFFFFFFFFu;    // atomicMin identity

    const int lane = gid & 63;
    const int ent  = gid >> 6;          // b*128 + tile
    const int b    = ent >> 7;
    const int tile = ent & 127;
    const int c31  = lane & 31, half = lane >> 5;

    const float* p = pred + ((size_t)(b * NPTS + tile * 32 + c31)) * 3;
    float x = p[0], y = p[1], z = p[2];
    Split2 X = split2(x), Y = split2(y), Z = split2(z);
    Split2 P2 = split2(fmaf(x, x, fmaf(y, y, z * z)));

    short8 f;
    if (half == 0) {
        f[0]=(short)X.h; f[1]=(short)Y.h; f[2]=(short)Z.h;
        f[3]=(short)X.m; f[4]=(short)Y.m; f[5]=(short)Z.m;
        f[6]=(short)X.h; f[7]=(short)Y.h;
    } else {
        f[0]=(short)Z.h; f[1]=(short)X.m; f[2]=(short)Y.m; f[3]=(short)Z.m;
        f[4]=ONEB;       f[5]=ONEB;       f[6]=(short)P2.h; f[7]=(short)P2.m;
    }
    Bfrag[gid] = f;
}

// ---- main: per block = (batch, 64 gt rows); sweep all 4096 pred cols ----
__global__ __launch_bounds__(TPBM, 8) void chamfer_mfma(
    const float* __restrict__ gt,
    uint* __restrict__ wspred,
    float* __restrict__ wsgt,
    const short8* __restrict__ Bfrag)
{
    const int bx    = blockIdx.x;      // 2048 = b(32) x panel(64)
    const int b     = bx >> 6;
    const int panel = bx & 63;
    const int tid   = threadIdx.x;
    const int lane  = tid & 63, wid = tid >> 6;
    const int rw    = wid >> 2;        // row half: 32 rows
    const int cq    = wid & 3;         // col quarter: 1024 cols
    const int c31   = lane & 31, half = lane >> 5;

    __shared__ short8 sB[4 * CHT * 64];   // 16 KB: [cq][t][lane]
    __shared__ uint   sPmin[NPTS];        // 16 KB: col-mins, uint-ordered
    __shared__ float  sred[64 * 4];       // 1 KB: gt-side [row_local][cq]

    for (int c = tid; c < NPTS; c += TPBM) sPmin[c] = 0x7F7FFFFFu;

    // A-frag: this wave's 32 gt rows, coords scaled by -2, g2 baked in.
    const float* gtb = gt + (size_t)b * NPTS * 3;
    const int row = panel * 64 + rw * 32 + c31;
    const float* ap = gtb + (size_t)row * 3;
    {
    }
    float x = ap[0], y = ap[1], z = ap[2];
    Split2 X = split2(-2.0f * x), Y = split2(-2.0f * y), Z = split2(-2.0f * z);
    Split2 G2 = split2(fmaf(x, x, fmaf(y, y, z * z)));
    short8 afr;
    if (half == 0) {
        afr[0]=(short)X.h; afr[1]=(short)Y.h; afr[2]=(short)Z.h;
        afr[3]=(short)X.h; afr[4]=(short)Y.h; afr[5]=(short)Z.h;
        afr[6]=(short)X.m; afr[7]=(short)Y.m;
    } else {
        afr[0]=(short)Z.m; afr[1]=(short)X.m; afr[2]=(short)Y.m; afr[3]=(short)Z.m;
        afr[4]=(short)G2.h; afr[5]=(short)G2.m; afr[6]=ONEB; afr[7]=ONEB;
    }

    float gm[16];
#pragma unroll
    for (int r = 0; r < 16; ++r) gm[r] = 1e30f;

    const size_t bfb = (size_t)b * (NBT * 64);
    const f32x16 zero = {0.f,0.f,0.f,0.f,0.f,0.f,0.f,0.f,
                         0.f,0.f,0.f,0.f,0.f,0.f,0.f,0.f};

    for (int ch = 0; ch < NCH; ++ch) {
        __syncthreads();   // prior chunk's reads done (ch=0: init visible)
        // stage 1024 entries (16 KB), 2 per thread, contiguous 16B runs
#pragma unroll
        for (int ps = 0; ps < 2; ++ps) {
            const int u   = ps * TPBM + tid;
            const int ucq = u >> 8, ut = (u >> 6) & 3, ul = u & 63;
            sB[u] = Bfrag[bfb + (size_t)((ucq * 32 + ch * CHT + ut) * 64 + ul)];
        }
        __syncthreads();   // stage visible

#pragma unroll
        for (int t = 0; t < CHT; ++t) {
            short8 bfr = sB[(cq * CHT + t) * 64 + lane];
            f32x16 acc = __builtin_amdgcn_mfma_f32_32x32x16_bf16(
                afr, bfr, zero, 0, 0, 0);

            // gt-side: running row-mins (16 v_min)
#pragma unroll
            for (int r = 0; r < 16; ++r) gm[r] = fminf(gm[r], acc[r]);

            // pred-side: min over this lane's 16 rows (v_min3 tree)
            float t0 = fminf(fminf(acc[0], acc[1]), acc[2]);
            float t1 = fminf(fminf(acc[3], acc[4]), acc[5]);
            float t2 = fminf(fminf(acc[6], acc[7]), acc[8]);
            float t3 = fminf(fminf(acc[9], acc[10]), acc[11]);
            float t4 = fminf(fminf(acc[12], acc[13]), acc[14]);
            float u0 = fminf(fminf(t0, t1), acc[15]);
            float u1 = fminf(fminf(t2, t3), t4);
            float dp = fmaxf(fminf(u0, u1), 1e-12f);  // >0: uint order==float
            // 64 lanes -> 32 contiguous addrs (2-way same-address, + rw wave)
            atomicMin(&sPmin[cq * 1024 + (ch * CHT + t) * 32 + c31],
                      __float_as_uint(dp));
        }
    }
    __syncthreads();   // sPmin complete

    // pred-side epilogue: batched guarded atomicMin, coalesced
    uint* wsb = wspred + (size_t)b * NPTS;
    for (int c = tid; c < NPTS; c += TPBM) {
        const uint mine = sPmin[c];
        if (mine < wsb[c]) atomicMin(&wsb[c], mine);
    }

    // gt-side: fold row-mins across the 32 cols (c31 lanes)
#pragma unroll
    for (int off = 1; off < 32; off <<= 1)
#pragma unroll
        for (int r = 0; r < 16; ++r)
            gm[r] = fminf(gm[r], __shfl_xor(gm[r], off, 64));
    if (c31 == 0) {
#pragma unroll
        for (int r = 0; r < 16; ++r)
            sred[(rw * 32 + (r & 3) + 8 * (r >> 2) + 4 * half) * 4 + cq] = gm[r];
    }
    __syncthreads();

    if (tid < 64) {   // wave 0: fold 4 cq, sqrt, sum -> wsgt[bx]
        float v = fminf(fminf(sred[tid * 4], sred[tid * 4 + 1]),
                        fminf(sred[tid * 4 + 2], sred[tid * 4 + 3]));
        float s = sqrtf(fmaxf(v, 1e-12f));
#pragma unroll
        for (int off = 32; off > 0; off >>= 1) s += __shfl_down(s, off, 64);
        if (tid == 0) wsgt[bx] = s;
    }
}

// ---- finish: sum sqrt(pred mins) + gt partials -> out ----
__global__ __launch_bounds__(TPBP) void chamfer_finish(
    const uint* __restrict__ wspred, const float* __restrict__ wsgt,
    float* __restrict__ out)
{
    __shared__ float swv[TPBP / 64];
    const int tid  = threadIdx.x;
    const int base = blockIdx.x * (TPBP * 4) + tid;   // 128 blocks x 1024

    float s = 0.0f;
#pragma unroll
    for (int r = 0; r < 4; ++r)
        s += sqrtf(__uint_as_float(wspred[base + r * TPBP]));
    if (blockIdx.x == 0) {
#pragma unroll
        for (int r = 0; r < 8; ++r)
            s += wsgt[tid + r * TPBP];   // 2048 per-block gt partials
    }

#pragma unroll
    for (int off = 32; off > 0; off >>= 1) s += __shfl_down(s, off, 64);
    const int wid = tid >> 6, lane = tid & 63;
    if (lane == 0) swv[wid] = s;
    __syncthreads();
    if (tid == 0) {
        float tot = swv[0] + swv[1] + swv[2] + swv[3];
        atomicAdd(out, tot * (1.0f / 131072.0f));
    }
}

extern "C" void kernel_launch(void* const* d_in, const int* in_sizes, int n_in,
                              void* d_out, int out_size, void* d_ws, size_t ws_size,
                              hipStream_t stream)
{
    const float* pred = (const float*)d_in[0];
    const float* gt   = (const float*)d_in[1];
    float* out        = (float*)d_out;

    // ws layout: [0,512K) wspred uints; [512K,+8K) wsgt; [1M,5M) Bfrag
    uint*   wspred = (uint*)d_ws;
    float*  wsgt   = (float*)((char*)d_ws + (512 << 10));
    short8* Bfrag  = (short8*)((char*)d_ws + (1 << 20));

    hipMemsetAsync(d_out, 0, sizeof(float), stream);

    chamfer_prep<<<dim3((32 * NBT * 64) / TPBP), dim3(TPBP), 0, stream>>>(
        pred, Bfrag, wspred);
    chamfer_mfma<<<dim3(GRID_MAIN), dim3(TPBM), 0, stream>>>(
        gt, wspred, wsgt, Bfrag);
    chamfer_finish<<<dim3(128), dim3(TPBP), 0, stream>>>(wspred, wsgt, out);
}